// Round 2
// baseline (43026.108 us; speedup 1.0000x reference)
//
#include <hip/hip_runtime.h>
#include <hip/hip_bf16.h>
#include <hip/hip_cooperative_groups.h>
#include <math.h>

namespace cg = cooperative_groups;

// Problem dims (fixed by the reference)
#define T_  512
#define B_  64
#define I_  512
#define H_  1024
#define HX_ 1536
#define WPITCH 1560   // bf16 elems per weight row in LDS; 1560*2B=3120B=780dw, 780%32=12
                      // -> lane n covers banks {12n..12n+3} mod 32: n=0..7 distinct, 2-way
                      // overall = free (m136). 3120%16==0 so b128 reads stay aligned.
#define GP  17        // g_lds row pitch (fp32), odd -> spreads banks

typedef __attribute__((ext_vector_type(8))) short bf16x8;
typedef __attribute__((ext_vector_type(4))) float floatx4;

__device__ __forceinline__ float sigmoidf_(float v) { return 1.0f / (1.0f + __expf(-v)); }
__device__ __forceinline__ float tanhf_(float v) {
    float e = __expf(-2.0f * fabsf(v));
    float t = (1.0f - e) / (1.0f + e);
    return copysignf(t, v);
}
__device__ __forceinline__ short f2bf(float f) {
    union { __hip_bfloat16 b; short s; } u;
    u.b = __float2bfloat16(f);   // RNE
    return u.s;
}

// Persistent cooperative kernel: 256 blocks x 512 threads, 1 block/CU.
// Block bid owns hidden units j0..j0+3 (j0 = bid*4) -> 16 Wg rows
// (4 gates x 4 units) staged in LDS as bf16 ONCE. c state lives in LDS fp32
// for the whole sequence. h double-buffered in ws as bf16 [B][H].
// Wave layout: wv = tid>>6; w = wv&3 -> batch tile m0 = 16w; kh = wv>>2 -> K half.
// Each wave: one 16x16 MFMA accumulator over its K half (24 frags of K=32).
__global__ __launch_bounds__(512, 1) void lstm_all(
    const float* __restrict__ x,
    const float* __restrict__ Wf, const float* __restrict__ bfp,
    const float* __restrict__ Wi, const float* __restrict__ bip,
    const float* __restrict__ Wc, const float* __restrict__ bcp,
    const float* __restrict__ Wo, const float* __restrict__ bop,
    float* __restrict__ out,
    __hip_bfloat16* __restrict__ hbuf)      // ws: 2 x [B_][H_] bf16
{
    __shared__ __align__(16) short Wlds[16 * WPITCH];   // 49,920 B
    __shared__ __align__(16) float g_lds[64 * GP];      //  4,352 B
    __shared__ float c_state[256];                      //  1,024 B

    const int tid  = threadIdx.x;
    const int bid  = blockIdx.x;
    const int lane = tid & 63;
    const int wv   = tid >> 6;       // 0..7
    const int w    = wv & 3;         // M tile
    const int kh   = wv >> 2;        // K half: 0 -> k[0,768), 1 -> k[768,1536)
    const int m0   = w * 16;
    const int n16  = lane & 15;      // A row (batch m0+n16) AND B col
    const int quad = lane >> 4;      // 0..3 -> k sub-chunk quad*8
    const int j0   = bid * 4;

    // ---- phase 0: stage 16 weight rows -> LDS bf16; biases; zero h0/c ----
    #pragma unroll
    for (int n = 0; n < 16; ++n) {
        const float* src;
        switch (n >> 2) {
            case 0:  src = Wf; break;
            case 1:  src = Wi; break;
            case 2:  src = Wc; break;
            default: src = Wo; break;
        }
        src += (size_t)(j0 + (n & 3)) * HX_;
        for (int off = tid; off < HX_; off += 512)
            Wlds[n * WPITCH + off] = f2bf(src[off]);
    }

    float bias_f = 0.f, bias_i = 0.f, bias_c = 0.f, bias_o = 0.f;
    if (tid < 256) {
        const int u = tid & 3;
        bias_f = bfp[j0 + u]; bias_i = bip[j0 + u];
        bias_c = bcp[j0 + u]; bias_o = bop[j0 + u];
        c_state[tid] = 0.0f;
    }
    {   // zero h slot 0: 256 blocks x 512 threads >= 65536 elems
        int idx = bid * 512 + tid;
        if (idx < B_ * H_) hbuf[idx] = __float2bfloat16(0.0f);
    }
    __syncthreads();
    cg::this_grid().sync();

    for (int t = 0; t < T_; ++t) {
        const short* __restrict__ hsrc =
            (const short*)(hbuf + (size_t)(t & 1) * (B_ * H_));
        __hip_bfloat16* __restrict__ hdst =
            hbuf + (size_t)((t + 1) & 1) * (B_ * H_);
        const float* __restrict__ xt = x + (size_t)t * (B_ * I_);

        // ---- gate GEMM: this wave's 16x16 tile over its K half ----
        floatx4 acc = {0.f, 0.f, 0.f, 0.f};
        const short* __restrict__ hrow = hsrc + (m0 + n16) * H_;
        const float* __restrict__ xrow = xt + (m0 + n16) * I_;
        const short* __restrict__ wrow = &Wlds[n16 * WPITCH];

        if (kh == 0) {
            // k in [0,768): all from h
            #pragma unroll 8
            for (int kf = 0; kf < 24; ++kf) {
                const int kl = kf * 32 + quad * 8;
                bf16x8 av = *(const bf16x8*)(hrow + kl);
                bf16x8 bv = *(const bf16x8*)(wrow + kl);
                acc = __builtin_amdgcn_mfma_f32_16x16x32_bf16(av, bv, acc, 0, 0, 0);
            }
        } else {
            // k in [768,1024): from h
            #pragma unroll
            for (int kf = 0; kf < 8; ++kf) {
                const int kl = 768 + kf * 32 + quad * 8;
                bf16x8 av = *(const bf16x8*)(hrow + kl);
                bf16x8 bv = *(const bf16x8*)(wrow + kl);
                acc = __builtin_amdgcn_mfma_f32_16x16x32_bf16(av, bv, acc, 0, 0, 0);
            }
            // k in [1024,1536): from x (fp32 -> bf16 on the fly)
            #pragma unroll 4
            for (int kf = 0; kf < 16; ++kf) {
                const int kl = 1024 + kf * 32 + quad * 8;
                const float* xp = xrow + (kl - 1024);
                float4 xa = *(const float4*)xp;
                float4 xb = *(const float4*)(xp + 4);
                union { short s[8]; bf16x8 v; } u;
                u.s[0] = f2bf(xa.x); u.s[1] = f2bf(xa.y);
                u.s[2] = f2bf(xa.z); u.s[3] = f2bf(xa.w);
                u.s[4] = f2bf(xb.x); u.s[5] = f2bf(xb.y);
                u.s[6] = f2bf(xb.z); u.s[7] = f2bf(xb.w);
                bf16x8 bv = *(const bf16x8*)(wrow + kl);
                acc = __builtin_amdgcn_mfma_f32_16x16x32_bf16(u.v, bv, acc, 0, 0, 0);
            }
        }

        // ---- combine the two K halves in LDS ----
        // C/D layout: col = lane&15, row(within 16) = quad*4 + reg  [m89/m91]
        if (kh == 1) {
            #pragma unroll
            for (int i2 = 0; i2 < 4; ++i2)
                g_lds[(m0 + quad * 4 + i2) * GP + n16] = acc[i2];
        }
        __syncthreads();
        if (kh == 0) {
            #pragma unroll
            for (int i2 = 0; i2 < 4; ++i2)
                g_lds[(m0 + quad * 4 + i2) * GP + n16] += acc[i2];
        }
        __syncthreads();

        // ---- elementwise gate/state update: thread -> (batch b, unit u) ----
        if (tid < 256) {
            const int b = tid >> 2, u = tid & 3;
            float gf = g_lds[b * GP + u]      + bias_f;
            float gi = g_lds[b * GP + 4 + u]  + bias_i;
            float gc = g_lds[b * GP + 8 + u]  + bias_c;
            float go = g_lds[b * GP + 12 + u] + bias_o;
            float F  = sigmoidf_(gf);
            float In = sigmoidf_(gi);
            float O  = sigmoidf_(go);
            float G  = tanhf_(gc);
            float c  = F * c_state[tid] + In * G;
            c_state[tid] = c;
            float h  = O * tanhf_(c);
            hdst[b * H_ + j0 + u] = __float2bfloat16(h);
            out[(size_t)t * (B_ * H_) + b * H_ + j0 + u] = h;
        }
        __syncthreads();
        __threadfence();            // release h stores (agent scope)
        cg::this_grid().sync();     // device-wide barrier + acquire
    }
}

extern "C" void kernel_launch(void* const* d_in, const int* in_sizes, int n_in,
                              void* d_out, int out_size, void* d_ws, size_t ws_size,
                              hipStream_t stream) {
    const float* x  = (const float*)d_in[0];
    const float* Wf = (const float*)d_in[1];
    const float* bf = (const float*)d_in[2];
    const float* Wi = (const float*)d_in[3];
    const float* bi = (const float*)d_in[4];
    const float* Wc = (const float*)d_in[5];
    const float* bc = (const float*)d_in[6];
    const float* Wo = (const float*)d_in[7];
    const float* bo = (const float*)d_in[8];
    float* out = (float*)d_out;
    __hip_bfloat16* hbuf = (__hip_bfloat16*)d_ws;   // 256 KB

    void* args[] = { &x, &Wf, &bf, &Wi, &bi, &Wc, &bc, &Wo, &bo, &out, &hbuf };
    hipLaunchCooperativeKernel((const void*)lstm_all, dim3(256), dim3(512),
                               args, 0, stream);
}

// Round 3
// 8079.252 us; speedup vs baseline: 5.3255x; 5.3255x over previous
//
#include <hip/hip_runtime.h>
#include <hip/hip_bf16.h>
#include <math.h>

// Problem dims (fixed by the reference)
#define T_  512
#define B_  64
#define I_  512
#define H_  1024
#define HX_ 1536
#define NG  4096          // 4*H gate rows
#define GP  17            // g_lds pitch

typedef __attribute__((ext_vector_type(8))) short bf16x8;
typedef __attribute__((ext_vector_type(4))) float floatx4;

__device__ __forceinline__ float sigmoidf_(float v) { return 1.0f / (1.0f + __expf(-v)); }
__device__ __forceinline__ float tanhf_(float v) {
    float e = __expf(-2.0f * fabsf(v));
    float t = (1.0f - e) / (1.0f + e);
    return copysignf(t, v);
}
__device__ __forceinline__ short f2bf(float f) {
    union { __hip_bfloat16 b; short s; } u;
    u.b = __float2bfloat16(f);   // RNE
    return u.s;
}

// ---- prologue: pack Wg (4 x [H][HX] fp32) -> Wp [4096][HX] bf16, rows r=u*4+g;
//      pack biases the same way. Runs every call (ws is re-poisoned).
__global__ __launch_bounds__(256) void pack_w(
    const float* __restrict__ Wf, const float* __restrict__ Wi,
    const float* __restrict__ Wc, const float* __restrict__ Wo,
    const float* __restrict__ bf, const float* __restrict__ bi,
    const float* __restrict__ bc, const float* __restrict__ bo,
    short* __restrict__ Wp, float* __restrict__ bp)
{
    const int r = blockIdx.x;          // 0..4095
    const int u = r >> 2, g = r & 3;
    const float* src; const float* bsrc;
    switch (g) {
        case 0:  src = Wf; bsrc = bf; break;
        case 1:  src = Wi; bsrc = bi; break;
        case 2:  src = Wc; bsrc = bc; break;
        default: src = Wo; bsrc = bo; break;
    }
    src += (size_t)u * HX_;
    for (int off = threadIdx.x; off < HX_; off += 256)
        Wp[(size_t)r * HX_ + off] = f2bf(src[off]);
    if (threadIdx.x == 0) bp[r] = bsrc[u];
}

__global__ __launch_bounds__(256) void init_state(__hip_bfloat16* __restrict__ h0,
                                                  float* __restrict__ c0)
{
    int i = blockIdx.x * 256 + threadIdx.x;
    if (i < B_ * H_) { h0[i] = __float2bfloat16(0.0f); c0[i] = 0.0f; }
}

// ---- one timestep ----
// grid (256, 2): blockIdx.x = nt (16 gemm cols = 4 units x 4 gates),
//                blockIdx.y = mh (batch half: rows mh*32 .. +31)
// block 256 = 4 waves: w = wv&1 -> 16-row M tile; kh = wv>>1 -> K half.
// B operand (weights, bf16) and A operand (h bf16 / x fp32) read from L2.
__global__ __launch_bounds__(256) void lstm_step(
    const float* __restrict__ xt,        // [B][I] fp32
    const short* __restrict__ Wp,        // [4096][HX] bf16 packed
    const float* __restrict__ bp,        // [4096] packed biases
    const short* __restrict__ hsrc,      // [B][H] bf16
    __hip_bfloat16* __restrict__ hdst,   // [B][H] bf16
    float* __restrict__ cws,             // [512][128] block-local c state
    float* __restrict__ out_t)           // [B][H] fp32
{
    __shared__ __align__(16) float g_lds[32 * GP];
    __shared__ __align__(16) float hso[32 * 4];
    __shared__ __align__(16) short hsb[32 * 4];

    const int tid  = threadIdx.x;
    const int nt   = blockIdx.x;
    const int mh   = blockIdx.y;
    const int lane = tid & 63;
    const int wv   = tid >> 6;        // 0..3
    const int w    = wv & 1;          // M tile within the half
    const int kh   = wv >> 1;         // K half: 0 -> [0,768), 1 -> [768,1536)
    const int n16  = lane & 15;
    const int quad = lane >> 4;
    const int n0   = nt * 16;         // gemm col base (packed rows)
    const int j0   = nt * 4;          // hidden-unit base
    const int mrow = mh * 32 + w * 16 + n16;   // batch row for A

    floatx4 acc = {0.f, 0.f, 0.f, 0.f};
    const short* __restrict__ hrow = hsrc + mrow * H_;
    const float* __restrict__ xrow = xt + mrow * I_;
    const short* __restrict__ wrow = Wp + (size_t)(n0 + n16) * HX_;

    if (kh == 0) {
        // k in [0,768): all from h
        #pragma unroll
        for (int kf = 0; kf < 24; ++kf) {
            const int kl = kf * 32 + quad * 8;
            bf16x8 av = *(const bf16x8*)(hrow + kl);
            bf16x8 bv = *(const bf16x8*)(wrow + kl);
            acc = __builtin_amdgcn_mfma_f32_16x16x32_bf16(av, bv, acc, 0, 0, 0);
        }
    } else {
        // k in [768,1024): from h
        #pragma unroll
        for (int kf = 0; kf < 8; ++kf) {
            const int kl = 768 + kf * 32 + quad * 8;
            bf16x8 av = *(const bf16x8*)(hrow + kl);
            bf16x8 bv = *(const bf16x8*)(wrow + kl);
            acc = __builtin_amdgcn_mfma_f32_16x16x32_bf16(av, bv, acc, 0, 0, 0);
        }
        // k in [1024,1536): from x, fp32 -> bf16 on the fly
        #pragma unroll
        for (int kf = 0; kf < 16; ++kf) {
            const int kl = 1024 + kf * 32 + quad * 8;
            const float* xp = xrow + (kl - 1024);
            float4 xa = *(const float4*)xp;
            float4 xb = *(const float4*)(xp + 4);
            union { short s[8]; bf16x8 v; } u;
            u.s[0] = f2bf(xa.x); u.s[1] = f2bf(xa.y);
            u.s[2] = f2bf(xa.z); u.s[3] = f2bf(xa.w);
            u.s[4] = f2bf(xb.x); u.s[5] = f2bf(xb.y);
            u.s[6] = f2bf(xb.z); u.s[7] = f2bf(xb.w);
            bf16x8 bv = *(const bf16x8*)(wrow + kl);
            acc = __builtin_amdgcn_mfma_f32_16x16x32_bf16(u.v, bv, acc, 0, 0, 0);
        }
    }

    // ---- reduce the two K halves ----
    // C/D layout: col = lane&15, row = quad*4 + reg  [m89/m91; round-2 verified]
    if (kh == 1) {
        #pragma unroll
        for (int i2 = 0; i2 < 4; ++i2)
            g_lds[(w * 16 + quad * 4 + i2) * GP + n16] = acc[i2];
    }
    __syncthreads();
    if (kh == 0) {
        #pragma unroll
        for (int i2 = 0; i2 < 4; ++i2)
            g_lds[(w * 16 + quad * 4 + i2) * GP + n16] += acc[i2];
    }
    __syncthreads();

    // ---- elementwise update: thread -> (local batch b_loc, unit u) ----
    if (tid < 128) {
        const int b_loc = tid >> 2, u = tid & 3;
        float4 bias = *(const float4*)(bp + n0 + u * 4);
        float gf = g_lds[b_loc * GP + u * 4 + 0] + bias.x;
        float gi = g_lds[b_loc * GP + u * 4 + 1] + bias.y;
        float gc = g_lds[b_loc * GP + u * 4 + 2] + bias.z;
        float go = g_lds[b_loc * GP + u * 4 + 3] + bias.w;
        float F  = sigmoidf_(gf);
        float In = sigmoidf_(gi);
        float O  = sigmoidf_(go);
        float G  = tanhf_(gc);
        const int cidx = (mh * 256 + nt) * 128 + tid;   // block-local, coalesced
        float c = cws[cidx];
        c = F * c + In * G;
        cws[cidx] = c;
        float h = O * tanhf_(c);
        hso[b_loc * 4 + u] = h;
        hsb[b_loc * 4 + u] = f2bf(h);
    }
    __syncthreads();

    // ---- coalesced stores: one thread per batch row of the tile ----
    if (tid < 32) {
        const int gb = mh * 32 + tid;    // global batch
        *(float4*)(out_t + (size_t)gb * H_ + j0) = *(const float4*)(hso + tid * 4);
        *(short4*)((short*)hdst + (size_t)gb * H_ + j0) = *(const short4*)(hsb + tid * 4);
    }
}

extern "C" void kernel_launch(void* const* d_in, const int* in_sizes, int n_in,
                              void* d_out, int out_size, void* d_ws, size_t ws_size,
                              hipStream_t stream) {
    const float* x  = (const float*)d_in[0];
    const float* Wf = (const float*)d_in[1];
    const float* bf = (const float*)d_in[2];
    const float* Wi = (const float*)d_in[3];
    const float* bi = (const float*)d_in[4];
    const float* Wc = (const float*)d_in[5];
    const float* bc = (const float*)d_in[6];
    const float* Wo = (const float*)d_in[7];
    const float* bo = (const float*)d_in[8];
    float* out = (float*)d_out;

    // ws layout (bytes):
    //   Wp  : 4096*1536*2  = 12,582,912
    //   bp  : 4096*4       =     16,384
    //   h   : 2*64*1024*2  =    262,144
    //   c   : 512*128*4    =    262,144   -> total ~13.1 MB
    char* wsb = (char*)d_ws;
    short*          Wp   = (short*)wsb;                       wsb += (size_t)NG * HX_ * 2;
    float*          bp   = (float*)wsb;                       wsb += NG * 4;
    __hip_bfloat16* hbuf = (__hip_bfloat16*)wsb;              wsb += (size_t)2 * B_ * H_ * 2;
    float*          cws  = (float*)wsb;

    pack_w<<<NG, 256, 0, stream>>>(Wf, Wi, Wc, Wo, bf, bi, bc, bo, Wp, bp);
    init_state<<<(B_ * H_ + 255) / 256, 256, 0, stream>>>(hbuf, cws);

    for (int t = 0; t < T_; ++t) {
        const short* hsrc = (const short*)(hbuf + (size_t)(t & 1) * (B_ * H_));
        __hip_bfloat16* hdst = hbuf + (size_t)((t + 1) & 1) * (B_ * H_);
        lstm_step<<<dim3(256, 2), 256, 0, stream>>>(
            x + (size_t)t * B_ * I_,
            Wp, bp, hsrc, hdst, cws,
            out + (size_t)t * B_ * H_);
    }
}

// Round 4
// 7207.391 us; speedup vs baseline: 5.9697x; 1.1210x over previous
//
#include <hip/hip_runtime.h>
#include <hip/hip_bf16.h>
#include <math.h>

// Problem dims (fixed by the reference)
#define T_  512
#define B_  64
#define I_  512
#define H_  1024
#define HX_ 1536
#define NG  4096          // 4*H packed gate rows
#define RP  17            // reduce-buffer pitch (fp32)

typedef __attribute__((ext_vector_type(8))) short bf16x8;
typedef __attribute__((ext_vector_type(4))) float floatx4;

__device__ __forceinline__ float sigmoidf_(float v) { return 1.0f / (1.0f + __expf(-v)); }
__device__ __forceinline__ float tanhf_(float v) {
    float e = __expf(-2.0f * fabsf(v));
    float t = (1.0f - e) / (1.0f + e);
    return copysignf(t, v);
}
__device__ __forceinline__ short f2bf(float f) {
    union { __hip_bfloat16 b; short s; } u;
    u.b = __float2bfloat16(f);   // RNE
    return u.s;
}

// ---- prologue: pack Wg -> Wp [4096][HX] bf16, rows r = u*4+g; biases too ----
__global__ __launch_bounds__(256) void pack_w(
    const float* __restrict__ Wf, const float* __restrict__ Wi,
    const float* __restrict__ Wc, const float* __restrict__ Wo,
    const float* __restrict__ bf, const float* __restrict__ bi,
    const float* __restrict__ bc, const float* __restrict__ bo,
    short* __restrict__ Wp, float* __restrict__ bp)
{
    const int r = blockIdx.x;          // 0..4095
    const int u = r >> 2, g = r & 3;
    const float* src; const float* bsrc;
    switch (g) {
        case 0:  src = Wf; bsrc = bf; break;
        case 1:  src = Wi; bsrc = bi; break;
        case 2:  src = Wc; bsrc = bc; break;
        default: src = Wo; bsrc = bo; break;
    }
    src += (size_t)u * HX_;
    for (int off = threadIdx.x; off < HX_; off += 256)
        Wp[(size_t)r * HX_ + off] = f2bf(src[off]);
    if (threadIdx.x == 0) bp[r] = bsrc[u];
}

// ---- init: hx[0] = [h0=0 | bf16(x_0)], c = 0 ----
__global__ __launch_bounds__(256) void init_all(
    const float* __restrict__ x0, short* __restrict__ hx0, float* __restrict__ cws)
{
    int idx = blockIdx.x * 256 + threadIdx.x;
    if (idx < B_ * HX_) {
        int b = idx / HX_, p = idx % HX_;
        hx0[idx] = (p < H_) ? (short)0 : f2bf(x0[b * I_ + (p - H_)]);
    } else if (idx < B_ * HX_ + 512 * 128) {
        cws[idx - B_ * HX_] = 0.0f;
    }
}

// ---- one timestep ----
// grid (256 nt, 2 mh) x 512 threads = 8 waves: w = wv&1 (16-row M tile within the
// 32-batch half), kq = wv>>1 (K quarter, 384 elems = 12 frags of K=32).
// A = hx (bf16, merged h|x), B = packed weights; both straight from L2.
// One __syncthreads; epilogue sums 4 K-partials from LDS; spare wave stages
// bf16(x_{t+1}) into the destination hx buffer.
__global__ __launch_bounds__(512, 4) void lstm_step(
    const short* __restrict__ Wp,        // [4096][HX] bf16 packed
    const float* __restrict__ bp,        // [4096] packed biases
    const short* __restrict__ hxsrc,     // [B][HX] bf16
    short* __restrict__ hxdst,           // [B][HX] bf16
    const float* __restrict__ xnext,     // x_{t+1} [B][I] fp32, or nullptr
    float* __restrict__ cws,             // [512][128] block-local c state
    float* __restrict__ out_t)           // [B][H] fp32
{
    __shared__ __align__(16) float red[4 * 32 * RP];   // [kq][row 0..31][col 0..15]

    const int tid  = threadIdx.x;
    const int nt   = blockIdx.x;
    const int mh   = blockIdx.y;
    const int lane = tid & 63;
    const int wv   = tid >> 6;        // 0..7
    const int w    = wv & 1;          // M tile within the half
    const int kq   = wv >> 1;         // K quarter
    const int n16  = lane & 15;
    const int quad = lane >> 4;
    const int n0   = nt * 16;         // packed gate-col base
    const int j0   = nt * 4;          // hidden-unit base
    const int mrow = mh * 32 + w * 16 + n16;

    const short* __restrict__ arow = hxsrc + mrow * HX_ + kq * 384 + quad * 8;
    const short* __restrict__ brow = Wp + (size_t)(n0 + n16) * HX_ + kq * 384 + quad * 8;

    // Preload all 12 B fragments (weights: L2-resident) ...
    bf16x8 bfr[12];
    #pragma unroll
    for (int i = 0; i < 12; ++i) bfr[i] = *(const bf16x8*)(brow + i * 32);
    // ... and a depth-4 A prefetch pipeline.
    bf16x8 afr[4];
    #pragma unroll
    for (int i = 0; i < 4; ++i) afr[i] = *(const bf16x8*)(arow + i * 32);

    floatx4 acc = {0.f, 0.f, 0.f, 0.f};
    #pragma unroll
    for (int kf = 0; kf < 12; ++kf) {
        acc = __builtin_amdgcn_mfma_f32_16x16x32_bf16(afr[kf & 3], bfr[kf], acc, 0, 0, 0);
        if (kf + 4 < 12) afr[kf & 3] = *(const bf16x8*)(arow + (kf + 4) * 32);
    }

    // C/D layout: col = lane&15, row = quad*4 + reg  [verified rounds 2-3]
    #pragma unroll
    for (int i2 = 0; i2 < 4; ++i2)
        red[(kq * 32 + w * 16 + quad * 4 + i2) * RP + n16] = acc[i2];
    __syncthreads();

    if (tid < 128) {
        // thread -> (local batch b_loc, hidden unit u)
        const int b_loc = tid >> 2, u = tid & 3;
        float4 bias = *(const float4*)(bp + n0 + u * 4);
        float gv[4];
        #pragma unroll
        for (int gg = 0; gg < 4; ++gg) {
            const int col = u * 4 + gg;
            float s = red[(0 * 32 + b_loc) * RP + col]
                    + red[(1 * 32 + b_loc) * RP + col]
                    + red[(2 * 32 + b_loc) * RP + col]
                    + red[(3 * 32 + b_loc) * RP + col];
            gv[gg] = s;
        }
        float F  = sigmoidf_(gv[0] + bias.x);
        float In = sigmoidf_(gv[1] + bias.y);
        float G  = tanhf_(gv[2] + bias.z);
        float O  = sigmoidf_(gv[3] + bias.w);
        const int cidx = (mh * 256 + nt) * 128 + tid;   // block-local, coalesced
        float c = cws[cidx];
        c = F * c + In * G;
        cws[cidx] = c;
        float h = O * tanhf_(c);
        const int gb = mh * 32 + b_loc;
        out_t[(size_t)gb * H_ + j0 + u] = h;
        hxdst[gb * HX_ + j0 + u] = f2bf(h);
    } else if (tid < 192) {
        // stage bf16(x_{t+1}) into hxdst's x-part: 64 elems per block
        if (xnext) {
            const int e = (mh * 256 + nt) * 64 + (tid - 128);
            const int b = e >> 9, p = e & 511;
            hxdst[b * HX_ + H_ + p] = f2bf(xnext[e]);
        }
    }
}

extern "C" void kernel_launch(void* const* d_in, const int* in_sizes, int n_in,
                              void* d_out, int out_size, void* d_ws, size_t ws_size,
                              hipStream_t stream) {
    const float* x  = (const float*)d_in[0];
    const float* Wf = (const float*)d_in[1];
    const float* bf = (const float*)d_in[2];
    const float* Wi = (const float*)d_in[3];
    const float* bi = (const float*)d_in[4];
    const float* Wc = (const float*)d_in[5];
    const float* bc = (const float*)d_in[6];
    const float* Wo = (const float*)d_in[7];
    const float* bo = (const float*)d_in[8];
    float* out = (float*)d_out;

    // ws layout (bytes):
    //   Wp : 4096*1536*2 = 12,582,912
    //   bp : 4096*4      =     16,384
    //   hx : 2*64*1536*2 =    393,216
    //   c  : 512*128*4   =    262,144   -> total ~13.25 MB
    char*  wsb = (char*)d_ws;
    short* Wp  = (short*)wsb;            wsb += (size_t)NG * HX_ * 2;
    float* bp  = (float*)wsb;            wsb += NG * 4;
    short* hx0 = (short*)wsb;            wsb += (size_t)B_ * HX_ * 2;
    short* hx1 = (short*)wsb;            wsb += (size_t)B_ * HX_ * 2;
    float* cws = (float*)wsb;

    pack_w<<<NG, 256, 0, stream>>>(Wf, Wi, Wc, Wo, bf, bi, bc, bo, Wp, bp);
    init_all<<<(B_ * HX_ + 512 * 128 + 255) / 256, 256, 0, stream>>>(x, hx0, cws);

    for (int t = 0; t < T_; ++t) {
        const short* hxsrc = (t & 1) ? hx1 : hx0;
        short*       hxdst = (t & 1) ? hx0 : hx1;
        const float* xnext = (t + 1 < T_) ? (x + (size_t)(t + 1) * B_ * I_) : nullptr;
        lstm_step<<<dim3(256, 2), 512, 0, stream>>>(
            Wp, bp, hxsrc, hxdst, xnext, cws,
            out + (size_t)t * B_ * H_);
    }
}